// Round 18
// baseline (265.302 us; speedup 1.0000x reference)
//
#include <hip/hip_runtime.h>
#include <hip/hip_fp16.h>

#define HH 128
#define WW 128
#define NPIX (HH*WW)
#define NB 8
#define NHEADS 6
#define HD 32
#define SCALE 0.17677669529663687f
#define LOG2E 1.4426950408889634f
#define QSCALE (SCALE * LOG2E)

typedef _Float16 h2 __attribute__((ext_vector_type(2)));
typedef __fp16 g2 __attribute__((ext_vector_type(2)));
typedef _Float16 f16x4 __attribute__((ext_vector_type(4)));
typedef _Float16 f16x8 __attribute__((ext_vector_type(8)));
typedef float f4 __attribute__((ext_vector_type(4)));

#if __has_builtin(__builtin_amdgcn_exp2f)
#define EXP2(x) __builtin_amdgcn_exp2f(x)
#else
#define EXP2(x) exp2f(x)
#endif

#define LDK 40    // na2d Vt padded stride
union U4 { g2 p2[2]; f16x4 v4; };

// ---------------- prep: WT[z][n][k] fp16 from W[z][k][n] fp32 ----------------
__global__ __launch_bounds__(512) void prep_wt(
    const float* __restrict__ Wq, const float* __restrict__ Wk,
    const float* __restrict__ Wv, _Float16* __restrict__ wt)
{
    int idx = blockIdx.x * 512 + threadIdx.x;      // 3*36864 total
    int mat = idx / 36864, rem = idx % 36864;
    int k = rem / 192, n = rem % 192;
    const float* W = mat == 0 ? Wq : (mat == 1 ? Wk : Wv);
    wt[(size_t)mat * 36864 + (size_t)n * 192 + k] = (_Float16)W[(size_t)k * 192 + n];
}

__global__ __launch_bounds__(512) void prep_wo(
    const float* __restrict__ Wo, _Float16* __restrict__ woT)
{
    int idx = blockIdx.x * 512 + threadIdx.x;      // 36864
    int k = idx / 192, n = idx % 192;
    woT[(size_t)n * 192 + k] = (_Float16)Wo[(size_t)k * 192 + n];
}

// ---------------- MFMA projection v12: balanced q/kv blocks, interleaved dispatch ----------------
// 3072 blocks: per XCD 384 = 128 q-tiles (128 pix) + 256 kv-tiles (64 pix, k AND v from one
// ctx stage). Per-block MFMA work now equal (72 MFMAs) -> homogeneous tail. Dispatch pattern
// q,kv,kv repeating so heavy/light mix evenly through the launch.
__global__ __launch_bounds__(512, 4) void proj_mfma(
    const float* __restrict__ x, const float* __restrict__ ctx,
    const _Float16* __restrict__ wt,
    const float* __restrict__ bq, const float* __restrict__ bk, const float* __restrict__ bv,
    _Float16* __restrict__ qh, _Float16* __restrict__ kh, _Float16* __restrict__ vh)
{
    int bid = blockIdx.x;             // 3072
    int xcd = bid & 7;
    int i = bid >> 3;                 // 0..383
    int phase = i % 3;                // 0 -> q, 1/2 -> kv
    int base = i / 3;                 // 0..127
    bool is_q = (phase == 0);

    __shared__ _Float16 Ts[128 * 192];   // 48KB (q uses all; kv uses first 64 rows)

    int t = threadIdx.x;
    int lane = t & 63;
    int wid  = t >> 6;
    int lq = lane & 15;
    int lk = lane >> 4;

    if (is_q) {
        int m0 = (xcd * 128 + base) * 128;
        int b  = m0 / NPIX;
        int p0 = m0 % NPIX;
        const float* Ab = x + (size_t)b * 192 * NPIX + p0;
        int wm = wid & 1;
        int wn = wid >> 1;

        {   // stage 128 pix x 192 ch: 12 float4 NT loads/thread
            int pq = t & 31;
            int cg = t >> 5;
            int c_base = cg * 12;
            f4 ra[12];
            #pragma unroll
            for (int j = 0; j < 12; j++)
                ra[j] = __builtin_nontemporal_load((const f4*)&Ab[(size_t)(c_base + j) * NPIX + 4 * pq]);
            __builtin_amdgcn_sched_barrier(0);
            #pragma unroll
            for (int r = 0; r < 4; r++) {
                int pix = 4 * pq + r;
                int sw = (pix & 7) << 3;
                #pragma unroll
                for (int j4 = 0; j4 < 3; j4++) {
                    int c0 = c_base + j4 * 4;
                    U4 u;
                    u.p2[0] = __builtin_amdgcn_cvt_pkrtz(ra[j4 * 4][r],     ra[j4 * 4 + 1][r]);
                    u.p2[1] = __builtin_amdgcn_cvt_pkrtz(ra[j4 * 4 + 2][r], ra[j4 * 4 + 3][r]);
                    *(f16x4*)&Ts[pix * 192 + (c0 ^ sw)] = u.v4;
                }
            }
        }
        __syncthreads();

        const _Float16* WT = wt;
        f4 acc[12] = {};
        #pragma unroll
        for (int ks = 0; ks < 6; ks++) {
            f16x8 wf[3];
            #pragma unroll
            for (int ni = 0; ni < 3; ni++)
                wf[ni] = *(const f16x8*)&WT[(size_t)(wn * 48 + ni * 16 + lq) * 192 + ks * 32 + lk * 8];
            #pragma unroll
            for (int mi = 0; mi < 4; mi++) {
                int pix = wm * 64 + mi * 16 + lq;
                f16x8 pfr = *(const f16x8*)&Ts[pix * 192 + ((ks * 32 + lk * 8) ^ ((pix & 7) << 3))];
                __builtin_amdgcn_s_setprio(1);
                #pragma unroll
                for (int ni = 0; ni < 3; ni++)
                    acc[mi * 3 + ni] = __builtin_amdgcn_mfma_f32_16x16x32_f16(wf[ni], pfr, acc[mi * 3 + ni], 0, 0, 0);
                __builtin_amdgcn_s_setprio(0);
            }
        }
        __syncthreads();

        #pragma unroll
        for (int mi = 0; mi < 4; mi++) {
            int pix = wm * 64 + mi * 16 + lq;
            int sw = (pix & 7) << 3;
            #pragma unroll
            for (int ni = 0; ni < 3; ni++) {
                int n0 = wn * 48 + ni * 16 + lk * 4;
                f4 v = acc[mi * 3 + ni];
                f4 bb = *(const f4*)&bq[n0];
                U4 u;
                u.p2[0] = __builtin_amdgcn_cvt_pkrtz((v[0] + bb[0]) * QSCALE, (v[1] + bb[1]) * QSCALE);
                u.p2[1] = __builtin_amdgcn_cvt_pkrtz((v[2] + bb[2]) * QSCALE, (v[3] + bb[3]) * QSCALE);
                *(f16x4*)&Ts[pix * 192 + (n0 ^ sw)] = u.v4;
            }
        }
        __syncthreads();

        int p2 = t >> 2, qc = t & 3;
        int sw = (p2 & 7) << 3;
        #pragma unroll
        for (int g = 0; g < 6; g++) {
            f16x8 val = *(const f16x8*)&Ts[p2 * 192 + ((g * 32 + qc * 8) ^ sw)];
            *(f16x8*)(qh + ((size_t)(b * NHEADS + g) * NPIX + p0 + p2) * HD + qc * 8) = val;
        }
    } else {
        // kv tile: 64 pixels, ctx staged once, k then v computed
        int tile = xcd * 256 + 2 * base + (phase - 1);   // 0..2047
        int m0 = tile * 64;
        int b  = m0 / NPIX;
        int p0 = m0 % NPIX;
        const float* Ab = ctx + (size_t)b * 192 * NPIX + p0;
        int wm = wid & 1;          // 2 m-halves of 32 pixels
        int wn = wid >> 1;         // 4 n-quarters of 48 channels

        {   // stage 64 pix x 192 ch: 6 float4 NT loads/thread
            int pq = t & 15;
            int cg = t >> 4;       // 32 groups x 6 channels
            int c_base = cg * 6;
            f4 ra[6];
            #pragma unroll
            for (int j = 0; j < 6; j++)
                ra[j] = __builtin_nontemporal_load((const f4*)&Ab[(size_t)(c_base + j) * NPIX + 4 * pq]);
            __builtin_amdgcn_sched_barrier(0);
            #pragma unroll
            for (int r = 0; r < 4; r++) {
                int pix = 4 * pq + r;
                int sw = (pix & 7) << 3;
                // 6 channels -> one 4-pack + one 2-pack
                U4 u;
                u.p2[0] = __builtin_amdgcn_cvt_pkrtz(ra[0][r], ra[1][r]);
                u.p2[1] = __builtin_amdgcn_cvt_pkrtz(ra[2][r], ra[3][r]);
                if ((c_base & 3) == 0) {
                    *(f16x4*)&Ts[pix * 192 + (c_base ^ sw)] = u.v4;
                    *(g2*)&Ts[pix * 192 + ((c_base + 4) ^ sw)] = __builtin_amdgcn_cvt_pkrtz(ra[4][r], ra[5][r]);
                } else {   // c_base % 4 == 2: write 2 + 4
                    *(g2*)&Ts[pix * 192 + (c_base ^ sw)] = u.p2[0];
                    U4 v2;
                    v2.p2[0] = __builtin_amdgcn_cvt_pkrtz(ra[2][r], ra[3][r]);
                    v2.p2[1] = __builtin_amdgcn_cvt_pkrtz(ra[4][r], ra[5][r]);
                    *(f16x4*)&Ts[pix * 192 + ((c_base + 2) ^ sw)] = v2.v4;
                }
            }
        }
        __syncthreads();

        #pragma unroll
        for (int out = 0; out < 2; out++) {
            const _Float16* WT = wt + (size_t)(1 + out) * 36864;
            const float* bias = out == 0 ? bk : bv;
            _Float16* outp = out == 0 ? kh : vh;
            f4 acc[6] = {};
            #pragma unroll
            for (int ks = 0; ks < 6; ks++) {
                f16x8 wf[3];
                #pragma unroll
                for (int ni = 0; ni < 3; ni++)
                    wf[ni] = *(const f16x8*)&WT[(size_t)(wn * 48 + ni * 16 + lq) * 192 + ks * 32 + lk * 8];
                #pragma unroll
                for (int mi = 0; mi < 2; mi++) {
                    int pix = wm * 32 + mi * 16 + lq;
                    f16x8 pfr = *(const f16x8*)&Ts[pix * 192 + ((ks * 32 + lk * 8) ^ ((pix & 7) << 3))];
                    __builtin_amdgcn_s_setprio(1);
                    #pragma unroll
                    for (int ni = 0; ni < 3; ni++)
                        acc[mi * 3 + ni] = __builtin_amdgcn_mfma_f32_16x16x32_f16(wf[ni], pfr, acc[mi * 3 + ni], 0, 0, 0);
                    __builtin_amdgcn_s_setprio(0);
                }
            }
            #pragma unroll
            for (int mi = 0; mi < 2; mi++) {
                int p = p0 + wm * 32 + mi * 16 + lq;
                #pragma unroll
                for (int ni = 0; ni < 3; ni++) {
                    int n0 = wn * 48 + ni * 16 + lk * 4;
                    int g = n0 >> 5, d0 = n0 & 31;
                    f4 v = acc[mi * 3 + ni];
                    f4 bb = *(const f4*)&bias[n0];
                    U4 u;
                    u.p2[0] = __builtin_amdgcn_cvt_pkrtz(v[0] + bb[0], v[1] + bb[1]);
                    u.p2[1] = __builtin_amdgcn_cvt_pkrtz(v[2] + bb[2], v[3] + bb[3]);
                    *(f16x4*)(outp + ((size_t)(b * NHEADS + g) * NPIX + p) * HD + d0) = u.v4;
                }
            }
        }
    }
}

// ---------------- MFMA neighborhood attention v5: exp2 softmax + bias-as-C-in ----------------
#define NA2D_SMEM 68352          // 66560 (Vt) + 1764 (rpb) rounded

template<int K>
__device__ __forceinline__ void na2d_tile(
    const _Float16* __restrict__ qh, const _Float16* __restrict__ kh,
    const _Float16* __restrict__ vh, const float* __restrict__ rpb,
    _Float16* __restrict__ ah, char* smem, int b, int g_head, int hi, int ty, int tx)
{
    constexpr int NS = K / 2;
    constexpr int RW = 2 * K - 1;
    _Float16* Vt = (_Float16*)smem;
    float* rpbs = (float*)(smem + 66560);

    int t = threadIdx.x;
    size_t plane = (size_t)(b * NHEADS + g_head) * NPIX;
    int h0 = ty * 16, w0 = tx * 16;
    int rmin = min(max(h0 - NS, 0), HH - K);
    int rtop = min(max(h0 + 15 - NS, 0), HH - K);
    int rows_n = rtop + K - rmin;
    int cwin0 = min(max(w0 - NS, 0), WW - K);
    int ctop = min(max(w0 + 15 - NS, 0), WW - K);
    int cols_n = ctop + K - cwin0;

    for (int i = t; i < RW * RW; i += 512) rpbs[i] = rpb[(size_t)hi * RW * RW + i] * LOG2E;

    int ntask = rows_n * 128;
    for (int idx = t; idx < ntask; idx += 512) {
        int row = idx >> 7;
        int key = (idx >> 2) & 31;
        int dc  = idx & 3;
        f16x8 vvv = {0,0,0,0,0,0,0,0};
        if (key < cols_n) {
            size_t pix = plane + (size_t)(rmin + row) * WW + (cwin0 + key);
            vvv = *(const f16x8*)&vh[pix * HD + dc * 8];
        }
        int m = 8 * ((key & 15) >> 2) + 4 * (key >> 4) + (key & 3);
        #pragma unroll
        for (int j = 0; j < 8; j++)
            Vt[row * 1280 + (dc * 8 + j) * LDK + m] = vvv[j];
    }
    __syncthreads();

    int lane = t & 63, wid = t >> 6;
    int lq = lane & 15, lg = lane >> 4;
    int wq = w0 + lq;
    int c0q = min(max(wq - NS, 0), WW - K);
    int klo = c0q - cwin0;
    int shiftc = cwin0 - wq + K - 1;
    f4 zf4 = {0.f, 0.f, 0.f, 0.f};

    int rcx[2][4];
    bool vld[2][4];
    #pragma unroll
    for (int c = 0; c < 2; c++) {
        #pragma unroll
        for (int r = 0; r < 4; r++) {
            int key_local = c * 16 + 4 * lg + r;
            rcx[c][r] = min(max(key_local + shiftc, 0), RW - 1);
            vld[c][r] = (unsigned)(key_local - klo) < (unsigned)K;
        }
    }
    h2 one2 = {(_Float16)1.f, (_Float16)1.f};

    #pragma unroll 1
    for (int qi = 0; qi < 2; qi++) {
        int qr = wid * 2 + qi;
        int h = h0 + qr;
        int r0q = min(max(h - NS, 0), HH - K);
        int row_base = r0q - rmin;
        f16x8 qf = *(const f16x8*)&qh[(plane + (size_t)h * WW + w0 + lq) * HD + lg * 8];
        f4 acc0 = zf4, acc1 = zf4;
        float lsum = 0.f;

        #pragma unroll 1
        for (int ki = 0; ki < K; ki++) {
            int row = row_base + ki;
            int rel_r = r0q + ki - h + K - 1;
            const float* rrow = rpbs + rel_r * RW;
            // bias fragments as MFMA C-input (saves 8 VALU adds)
            f4 cb0, cb1;
            #pragma unroll
            for (int r = 0; r < 4; r++) { cb0[r] = rrow[rcx[0][r]]; cb1[r] = rrow[rcx[1][r]]; }

            const _Float16* kgrow = kh + (plane + (size_t)(rmin + row) * WW + cwin0) * HD;
            f16x8 a0 = *(const f16x8*)&kgrow[(size_t)lq * HD + lg * 8];
            f16x8 a1 = *(const f16x8*)&kgrow[(size_t)(16 + lq) * HD + lg * 8];
            __builtin_amdgcn_s_setprio(1);
            f4 s0 = __builtin_amdgcn_mfma_f32_16x16x32_f16(a0, qf, cb0, 0, 0, 0);
            f4 s1 = __builtin_amdgcn_mfma_f32_16x16x32_f16(a1, qf, cb1, 0, 0, 0);
            __builtin_amdgcn_s_setprio(0);

            float pf[2][4];
            #pragma unroll
            for (int c = 0; c < 2; c++) {
                #pragma unroll
                for (int r = 0; r < 4; r++) {
                    float sv = c ? s1[r] : s0[r];
                    pf[c][r] = vld[c][r] ? EXP2(sv) : 0.f;
                }
            }
            union { g2 p[4]; h2 ph[4]; f16x8 v; } P;
            P.p[0] = __builtin_amdgcn_cvt_pkrtz(pf[0][0], pf[0][1]);
            P.p[1] = __builtin_amdgcn_cvt_pkrtz(pf[0][2], pf[0][3]);
            P.p[2] = __builtin_amdgcn_cvt_pkrtz(pf[1][0], pf[1][1]);
            P.p[3] = __builtin_amdgcn_cvt_pkrtz(pf[1][2], pf[1][3]);
            lsum = __builtin_amdgcn_fdot2(P.ph[0], one2, lsum, false);
            lsum = __builtin_amdgcn_fdot2(P.ph[1], one2, lsum, false);
            lsum = __builtin_amdgcn_fdot2(P.ph[2], one2, lsum, false);
            lsum = __builtin_amdgcn_fdot2(P.ph[3], one2, lsum, false);

            const _Float16* vbase = &Vt[row * 1280 + lg * 8];
            f16x8 b0 = *(const f16x8*)&vbase[lq * LDK];
            f16x8 b1 = *(const f16x8*)&vbase[(16 + lq) * LDK];
            __builtin_amdgcn_s_setprio(1);
            acc0 = __builtin_amdgcn_mfma_f32_16x16x32_f16(P.v, b0, acc0, 0, 0, 0);
            acc1 = __builtin_amdgcn_mfma_f32_16x16x32_f16(P.v, b1, acc1, 0, 0, 0);
            __builtin_amdgcn_s_setprio(0);
        }

        lsum += __shfl_xor(lsum, 16);
        lsum += __shfl_xor(lsum, 32);
        float inv = 1.f / lsum;
        _Float16* obase = ah + (plane + (size_t)h * WW + w0) * HD;
        #pragma unroll
        for (int r = 0; r < 4; r++) {
            float ir = __shfl(inv, 4 * lg + r);
            obase[(4 * lg + r) * HD + lq]      = (_Float16)(acc0[r] * ir);
            obase[(4 * lg + r) * HD + lq + 16] = (_Float16)(acc1[r] * ir);
        }
    }
}

__global__ __launch_bounds__(512) void na2d_mfma(
    const _Float16* __restrict__ qh, const _Float16* __restrict__ kh,
    const _Float16* __restrict__ vh,
    const float* __restrict__ rpb0, const float* __restrict__ rpb1,
    const float* __restrict__ rpb2, _Float16* __restrict__ ah)
{
    extern __shared__ char smem[];
    int bid = blockIdx.x;
    int xcd = bid & 7;
    int i = bid >> 3;
    int phase = i >> 7;
    int j = i & 127;
    int lb = xcd * 128 + j;
    int bz = lb >> 6;
    int tile = lb & 63;
    int b = bz >> 1, hi = bz & 1;
    int ty = tile >> 3, tx = tile & 7;
    if (phase == 0)      na2d_tile<7>(qh, kh, vh, rpb0, ah, smem, b, 0 + hi, hi, ty, tx);
    else if (phase == 1) na2d_tile<9>(qh, kh, vh, rpb1, ah, smem, b, 2 + hi, hi, ty, tx);
    else                 na2d_tile<11>(qh, kh, vh, rpb2, ah, smem, b, 4 + hi, hi, ty, tx);
}

// ---------------- MFMA output projection (unchanged) ----------------
__global__ __launch_bounds__(512) void oproj_mfma(
    const _Float16* __restrict__ ah, const _Float16* __restrict__ woT,
    const float* __restrict__ bo, float* __restrict__ outp)
{
    int t = threadIdx.x;
    int m0 = blockIdx.x * 128;
    int b  = m0 / NPIX;
    int p0 = m0 % NPIX;

    int lane = t & 63;
    int wid  = t >> 6;
    int wm = wid & 1;
    int wn = wid >> 1;
    int lr = lane & 15;
    int lk = lane >> 4;

    f4 acc[4][3] = {};

    #pragma unroll
    for (int ks = 0; ks < 6; ks++) {
        const _Float16* abase = ah + (size_t)(b * NHEADS + ks) * NPIX * HD;
        f16x8 af[4], bf[3];
        #pragma unroll
        for (int mi = 0; mi < 4; mi++)
            af[mi] = *(const f16x8*)&abase[(size_t)(p0 + wm * 64 + mi * 16 + lr) * HD + lk * 8];
        #pragma unroll
        for (int ni = 0; ni < 3; ni++)
            bf[ni] = *(const f16x8*)&woT[(size_t)(wn * 48 + ni * 16 + lr) * 192 + ks * 32 + lk * 8];
        #pragma unroll
        for (int mi = 0; mi < 4; mi++)
            #pragma unroll
            for (int ni = 0; ni < 3; ni++)
                acc[mi][ni] = __builtin_amdgcn_mfma_f32_16x16x32_f16(af[mi], bf[ni], acc[mi][ni], 0, 0, 0);
    }

    #pragma unroll
    for (int ni = 0; ni < 3; ni++) {
        int n = wn * 48 + ni * 16 + lr;
        float bb = bo[n];
        float* obase = outp + ((size_t)b * 192 + n) * NPIX + p0 + wm * 64;
        #pragma unroll
        for (int mi = 0; mi < 4; mi++) {
            f4 v = acc[mi][ni];
            v[0] += bb; v[1] += bb; v[2] += bb; v[3] += bb;
            *(f4*)&obase[mi * 16 + lk * 4] = v;
        }
    }
}

extern "C" void kernel_launch(void* const* d_in, const int* in_sizes, int n_in,
                              void* d_out, int out_size, void* d_ws, size_t ws_size,
                              hipStream_t stream) {
    const float* x    = (const float*)d_in[0];
    const float* ctx  = (const float*)d_in[1];
    const float* Wq   = (const float*)d_in[2];
    const float* bq   = (const float*)d_in[3];
    const float* Wk   = (const float*)d_in[4];
    const float* bk   = (const float*)d_in[5];
    const float* Wv   = (const float*)d_in[6];
    const float* bv   = (const float*)d_in[7];
    const float* Wo   = (const float*)d_in[8];
    const float* bo   = (const float*)d_in[9];
    const float* rpb0 = (const float*)d_in[10];
    const float* rpb1 = (const float*)d_in[11];
    const float* rpb2 = (const float*)d_in[12];

    size_t N = (size_t)NB * NHEADS * NPIX * HD;   // 25,165,824 fp16 elements = 50.33MB
    _Float16* qh = (_Float16*)d_ws;
    _Float16* kh = qh + N;
    _Float16* vh = kh + N;
    _Float16* ah = vh + N;
    float* outp = (float*)d_out;

    // parking: WT fp16 in second half of d_out (dead until oproj); woT in qh (dead after na2d)
    _Float16* wt  = (_Float16*)d_out + N;
    _Float16* woT = qh;

    (void)hipFuncSetAttribute((const void*)na2d_mfma,
                              hipFuncAttributeMaxDynamicSharedMemorySize, NA2D_SMEM);

    prep_wt<<<216, 512, 0, stream>>>(Wq, Wk, Wv, wt);
    proj_mfma<<<3072, 512, 0, stream>>>(x, ctx, wt, bq, bk, bv, qh, kh, vh);
    na2d_mfma<<<3072, 512, NA2D_SMEM, stream>>>(qh, kh, vh, rpb0, rpb1, rpb2, ah);
    prep_wo<<<72, 512, 0, stream>>>(Wo, woT);
    oproj_mfma<<<1024, 512, 0, stream>>>(ah, woT, bo, outp);
}

// Round 19
// 230.240 us; speedup vs baseline: 1.1523x; 1.1523x over previous
//
#include <hip/hip_runtime.h>
#include <hip/hip_fp16.h>

#define HH 128
#define WW 128
#define NPIX (HH*WW)
#define NB 8
#define NHEADS 6
#define HD 32
#define SCALE 0.17677669529663687f
#define LOG2E 1.4426950408889634f
#define QSCALE (SCALE * LOG2E)

typedef _Float16 h2 __attribute__((ext_vector_type(2)));
typedef __fp16 g2 __attribute__((ext_vector_type(2)));
typedef _Float16 f16x4 __attribute__((ext_vector_type(4)));
typedef _Float16 f16x8 __attribute__((ext_vector_type(8)));
typedef float f4 __attribute__((ext_vector_type(4)));

#if __has_builtin(__builtin_amdgcn_exp2f)
#define EXP2(x) __builtin_amdgcn_exp2f(x)
#else
#define EXP2(x) exp2f(x)
#endif

#define LDK 40    // na2d Vt padded stride
union U4 { g2 p2[2]; f16x4 v4; };

// ---------------- prep: WT[z][n][k] fp16 from W[z][k][n] fp32 ----------------
__global__ __launch_bounds__(512) void prep_wt(
    const float* __restrict__ Wq, const float* __restrict__ Wk,
    const float* __restrict__ Wv, _Float16* __restrict__ wt)
{
    int idx = blockIdx.x * 512 + threadIdx.x;      // 3*36864 total
    int mat = idx / 36864, rem = idx % 36864;
    int k = rem / 192, n = rem % 192;
    const float* W = mat == 0 ? Wq : (mat == 1 ? Wk : Wv);
    wt[(size_t)mat * 36864 + (size_t)n * 192 + k] = (_Float16)W[(size_t)k * 192 + n];
}

__global__ __launch_bounds__(512) void prep_wo(
    const float* __restrict__ Wo, _Float16* __restrict__ woT)
{
    int idx = blockIdx.x * 512 + threadIdx.x;      // 36864
    int k = idx / 192, n = idx % 192;
    woT[(size_t)n * 192 + k] = (_Float16)Wo[(size_t)k * 192 + n];
}

// ---------------- MFMA projection v11 (R17 exactly: best measured ~104us) ----------------
__global__ __launch_bounds__(512, 4) void proj_mfma(
    const float* __restrict__ x, const float* __restrict__ ctx,
    const _Float16* __restrict__ wt,
    const float* __restrict__ bq, const float* __restrict__ bk, const float* __restrict__ bv,
    _Float16* __restrict__ qh, _Float16* __restrict__ kh, _Float16* __restrict__ vh)
{
    int bid = blockIdx.x;             // 2048
    int xcd = bid & 7;
    int i = bid >> 3;                 // 0..255
    bool is_q = (i < 128);
    int xb = xcd * 128 + (is_q ? i : i - 128);

    const float* A = is_q ? x : ctx;

    __shared__ _Float16 Ts[128 * 192];   // 48KB; idx = pix*192 + (off ^ ((pix&7)<<3))

    int t = threadIdx.x;
    int m0 = xb * 128;
    int b  = m0 / NPIX;
    int p0 = m0 % NPIX;
    const float* Ab = A + (size_t)b * 192 * NPIX + p0;

    int lane = t & 63;
    int wid  = t >> 6;
    int wm = wid & 1;
    int wn = wid >> 1;
    int lq = lane & 15;
    int lk = lane >> 4;

    // ---- stage A tile: 12 x float4 NT loads/thread, swizzled 8B LDS writes ----
    {
        int pq = t & 31;
        int cg = t >> 5;
        int c_base = cg * 12;
        f4 ra[12];
        #pragma unroll
        for (int j = 0; j < 12; j++)
            ra[j] = __builtin_nontemporal_load((const f4*)&Ab[(size_t)(c_base + j) * NPIX + 4 * pq]);
        __builtin_amdgcn_sched_barrier(0);
        #pragma unroll
        for (int r = 0; r < 4; r++) {
            int pix = 4 * pq + r;
            int sw = (pix & 7) << 3;
            #pragma unroll
            for (int j4 = 0; j4 < 3; j4++) {
                int c0 = c_base + j4 * 4;
                U4 u;
                u.p2[0] = __builtin_amdgcn_cvt_pkrtz(ra[j4 * 4][r],     ra[j4 * 4 + 1][r]);
                u.p2[1] = __builtin_amdgcn_cvt_pkrtz(ra[j4 * 4 + 2][r], ra[j4 * 4 + 3][r]);
                *(f16x4*)&Ts[pix * 192 + (c0 ^ sw)] = u.v4;
            }
        }
    }
    __syncthreads();

    if (is_q) {
        const _Float16* WT = wt;
        f4 acc[12] = {};
        #pragma unroll
        for (int ks = 0; ks < 6; ks++) {
            f16x8 wf[3];
            #pragma unroll
            for (int ni = 0; ni < 3; ni++)
                wf[ni] = *(const f16x8*)&WT[(size_t)(wn * 48 + ni * 16 + lq) * 192 + ks * 32 + lk * 8];
            #pragma unroll
            for (int mi = 0; mi < 4; mi++) {
                int pix = wm * 64 + mi * 16 + lq;
                f16x8 pfr = *(const f16x8*)&Ts[pix * 192 + ((ks * 32 + lk * 8) ^ ((pix & 7) << 3))];
                __builtin_amdgcn_s_setprio(1);
                #pragma unroll
                for (int ni = 0; ni < 3; ni++)
                    acc[mi * 3 + ni] = __builtin_amdgcn_mfma_f32_16x16x32_f16(wf[ni], pfr, acc[mi * 3 + ni], 0, 0, 0);
                __builtin_amdgcn_s_setprio(0);
            }
        }
        __syncthreads();

        #pragma unroll
        for (int mi = 0; mi < 4; mi++) {
            int pix = wm * 64 + mi * 16 + lq;
            int sw = (pix & 7) << 3;
            #pragma unroll
            for (int ni = 0; ni < 3; ni++) {
                int n0 = wn * 48 + ni * 16 + lk * 4;
                f4 v = acc[mi * 3 + ni];
                f4 bb = *(const f4*)&bq[n0];
                U4 u;
                u.p2[0] = __builtin_amdgcn_cvt_pkrtz((v[0] + bb[0]) * QSCALE, (v[1] + bb[1]) * QSCALE);
                u.p2[1] = __builtin_amdgcn_cvt_pkrtz((v[2] + bb[2]) * QSCALE, (v[3] + bb[3]) * QSCALE);
                *(f16x4*)&Ts[pix * 192 + (n0 ^ sw)] = u.v4;
            }
        }
        __syncthreads();

        int p2 = t >> 2, qc = t & 3;
        int sw = (p2 & 7) << 3;
        #pragma unroll
        for (int g = 0; g < 6; g++) {
            f16x8 val = *(const f16x8*)&Ts[p2 * 192 + ((g * 32 + qc * 8) ^ sw)];
            *(f16x8*)(qh + ((size_t)(b * NHEADS + g) * NPIX + p0 + p2) * HD + qc * 8) = val;
        }
    } else {
        #pragma unroll
        for (int out = 0; out < 2; out++) {
            const _Float16* WT = wt + (size_t)(1 + out) * 36864;
            const float* bias = out == 0 ? bk : bv;
            _Float16* outp = out == 0 ? kh : vh;
            f4 acc[12] = {};
            #pragma unroll
            for (int ks = 0; ks < 6; ks++) {
                f16x8 wf[3];
                #pragma unroll
                for (int ni = 0; ni < 3; ni++)
                    wf[ni] = *(const f16x8*)&WT[(size_t)(wn * 48 + ni * 16 + lq) * 192 + ks * 32 + lk * 8];
                #pragma unroll
                for (int mi = 0; mi < 4; mi++) {
                    int pix = wm * 64 + mi * 16 + lq;
                    f16x8 pfr = *(const f16x8*)&Ts[pix * 192 + ((ks * 32 + lk * 8) ^ ((pix & 7) << 3))];
                    __builtin_amdgcn_s_setprio(1);
                    #pragma unroll
                    for (int ni = 0; ni < 3; ni++)
                        acc[mi * 3 + ni] = __builtin_amdgcn_mfma_f32_16x16x32_f16(wf[ni], pfr, acc[mi * 3 + ni], 0, 0, 0);
                    __builtin_amdgcn_s_setprio(0);
                }
            }
            #pragma unroll
            for (int mi = 0; mi < 4; mi++) {
                int p = p0 + wm * 64 + mi * 16 + lq;
                #pragma unroll
                for (int ni = 0; ni < 3; ni++) {
                    int n0 = wn * 48 + ni * 16 + lk * 4;
                    int g = n0 >> 5, d0 = n0 & 31;
                    f4 v = acc[mi * 3 + ni];
                    f4 bb = *(const f4*)&bias[n0];
                    U4 u;
                    u.p2[0] = __builtin_amdgcn_cvt_pkrtz(v[0] + bb[0], v[1] + bb[1]);
                    u.p2[1] = __builtin_amdgcn_cvt_pkrtz(v[2] + bb[2], v[3] + bb[3]);
                    *(f16x4*)(outp + ((size_t)(b * NHEADS + g) * NPIX + p) * HD + d0) = u.v4;
                }
            }
        }
    }
}

// ---------------- MFMA neighborhood attention v5: exp2 softmax + bias-as-C-in ----------------
#define NA2D_SMEM 68352          // 66560 (Vt) + 1764 (rpb) rounded

template<int K>
__device__ __forceinline__ void na2d_tile(
    const _Float16* __restrict__ qh, const _Float16* __restrict__ kh,
    const _Float16* __restrict__ vh, const float* __restrict__ rpb,
    _Float16* __restrict__ ah, char* smem, int b, int g_head, int hi, int ty, int tx)
{
    constexpr int NS = K / 2;
    constexpr int RW = 2 * K - 1;
    _Float16* Vt = (_Float16*)smem;
    float* rpbs = (float*)(smem + 66560);

    int t = threadIdx.x;
    size_t plane = (size_t)(b * NHEADS + g_head) * NPIX;
    int h0 = ty * 16, w0 = tx * 16;
    int rmin = min(max(h0 - NS, 0), HH - K);
    int rtop = min(max(h0 + 15 - NS, 0), HH - K);
    int rows_n = rtop + K - rmin;
    int cwin0 = min(max(w0 - NS, 0), WW - K);
    int ctop = min(max(w0 + 15 - NS, 0), WW - K);
    int cols_n = ctop + K - cwin0;

    for (int i = t; i < RW * RW; i += 512) rpbs[i] = rpb[(size_t)hi * RW * RW + i] * LOG2E;

    int ntask = rows_n * 128;
    for (int idx = t; idx < ntask; idx += 512) {
        int row = idx >> 7;
        int key = (idx >> 2) & 31;
        int dc  = idx & 3;
        f16x8 vvv = {0,0,0,0,0,0,0,0};
        if (key < cols_n) {
            size_t pix = plane + (size_t)(rmin + row) * WW + (cwin0 + key);
            vvv = *(const f16x8*)&vh[pix * HD + dc * 8];
        }
        int m = 8 * ((key & 15) >> 2) + 4 * (key >> 4) + (key & 3);
        #pragma unroll
        for (int j = 0; j < 8; j++)
            Vt[row * 1280 + (dc * 8 + j) * LDK + m] = vvv[j];
    }
    __syncthreads();

    int lane = t & 63, wid = t >> 6;
    int lq = lane & 15, lg = lane >> 4;
    int wq = w0 + lq;
    int c0q = min(max(wq - NS, 0), WW - K);
    int klo = c0q - cwin0;
    int shiftc = cwin0 - wq + K - 1;
    f4 zf4 = {0.f, 0.f, 0.f, 0.f};

    int rcx[2][4];
    bool vld[2][4];
    #pragma unroll
    for (int c = 0; c < 2; c++) {
        #pragma unroll
        for (int r = 0; r < 4; r++) {
            int key_local = c * 16 + 4 * lg + r;
            rcx[c][r] = min(max(key_local + shiftc, 0), RW - 1);
            vld[c][r] = (unsigned)(key_local - klo) < (unsigned)K;
        }
    }
    h2 one2 = {(_Float16)1.f, (_Float16)1.f};

    #pragma unroll 1
    for (int qi = 0; qi < 2; qi++) {
        int qr = wid * 2 + qi;
        int h = h0 + qr;
        int r0q = min(max(h - NS, 0), HH - K);
        int row_base = r0q - rmin;
        f16x8 qf = *(const f16x8*)&qh[(plane + (size_t)h * WW + w0 + lq) * HD + lg * 8];
        f4 acc0 = zf4, acc1 = zf4;
        float lsum = 0.f;

        #pragma unroll 1
        for (int ki = 0; ki < K; ki++) {
            int row = row_base + ki;
            int rel_r = r0q + ki - h + K - 1;
            const float* rrow = rpbs + rel_r * RW;
            f4 cb0, cb1;
            #pragma unroll
            for (int r = 0; r < 4; r++) { cb0[r] = rrow[rcx[0][r]]; cb1[r] = rrow[rcx[1][r]]; }

            const _Float16* kgrow = kh + (plane + (size_t)(rmin + row) * WW + cwin0) * HD;
            f16x8 a0 = *(const f16x8*)&kgrow[(size_t)lq * HD + lg * 8];
            f16x8 a1 = *(const f16x8*)&kgrow[(size_t)(16 + lq) * HD + lg * 8];
            __builtin_amdgcn_s_setprio(1);
            f4 s0 = __builtin_amdgcn_mfma_f32_16x16x32_f16(a0, qf, cb0, 0, 0, 0);
            f4 s1 = __builtin_amdgcn_mfma_f32_16x16x32_f16(a1, qf, cb1, 0, 0, 0);
            __builtin_amdgcn_s_setprio(0);

            float pf[2][4];
            #pragma unroll
            for (int c = 0; c < 2; c++) {
                #pragma unroll
                for (int r = 0; r < 4; r++) {
                    float sv = c ? s1[r] : s0[r];
                    pf[c][r] = vld[c][r] ? EXP2(sv) : 0.f;
                }
            }
            union { g2 p[4]; h2 ph[4]; f16x8 v; } P;
            P.p[0] = __builtin_amdgcn_cvt_pkrtz(pf[0][0], pf[0][1]);
            P.p[1] = __builtin_amdgcn_cvt_pkrtz(pf[0][2], pf[0][3]);
            P.p[2] = __builtin_amdgcn_cvt_pkrtz(pf[1][0], pf[1][1]);
            P.p[3] = __builtin_amdgcn_cvt_pkrtz(pf[1][2], pf[1][3]);
            lsum = __builtin_amdgcn_fdot2(P.ph[0], one2, lsum, false);
            lsum = __builtin_amdgcn_fdot2(P.ph[1], one2, lsum, false);
            lsum = __builtin_amdgcn_fdot2(P.ph[2], one2, lsum, false);
            lsum = __builtin_amdgcn_fdot2(P.ph[3], one2, lsum, false);

            const _Float16* vbase = &Vt[row * 1280 + lg * 8];
            f16x8 b0 = *(const f16x8*)&vbase[lq * LDK];
            f16x8 b1 = *(const f16x8*)&vbase[(16 + lq) * LDK];
            __builtin_amdgcn_s_setprio(1);
            acc0 = __builtin_amdgcn_mfma_f32_16x16x32_f16(P.v, b0, acc0, 0, 0, 0);
            acc1 = __builtin_amdgcn_mfma_f32_16x16x32_f16(P.v, b1, acc1, 0, 0, 0);
            __builtin_amdgcn_s_setprio(0);
        }

        lsum += __shfl_xor(lsum, 16);
        lsum += __shfl_xor(lsum, 32);
        float inv = 1.f / lsum;
        _Float16* obase = ah + (plane + (size_t)h * WW + w0) * HD;
        #pragma unroll
        for (int r = 0; r < 4; r++) {
            float ir = __shfl(inv, 4 * lg + r);
            obase[(4 * lg + r) * HD + lq]      = (_Float16)(acc0[r] * ir);
            obase[(4 * lg + r) * HD + lq + 16] = (_Float16)(acc1[r] * ir);
        }
    }
}

__global__ __launch_bounds__(512) void na2d_mfma(
    const _Float16* __restrict__ qh, const _Float16* __restrict__ kh,
    const _Float16* __restrict__ vh,
    const float* __restrict__ rpb0, const float* __restrict__ rpb1,
    const float* __restrict__ rpb2, _Float16* __restrict__ ah)
{
    extern __shared__ char smem[];
    int bid = blockIdx.x;
    int xcd = bid & 7;
    int i = bid >> 3;
    int phase = i >> 7;
    int j = i & 127;
    int lb = xcd * 128 + j;
    int bz = lb >> 6;
    int tile = lb & 63;
    int b = bz >> 1, hi = bz & 1;
    int ty = tile >> 3, tx = tile & 7;
    if (phase == 0)      na2d_tile<7>(qh, kh, vh, rpb0, ah, smem, b, 0 + hi, hi, ty, tx);
    else if (phase == 1) na2d_tile<9>(qh, kh, vh, rpb1, ah, smem, b, 2 + hi, hi, ty, tx);
    else                 na2d_tile<11>(qh, kh, vh, rpb2, ah, smem, b, 4 + hi, hi, ty, tx);
}

// ---------------- MFMA output projection (unchanged) ----------------
__global__ __launch_bounds__(512) void oproj_mfma(
    const _Float16* __restrict__ ah, const _Float16* __restrict__ woT,
    const float* __restrict__ bo, float* __restrict__ outp)
{
    int t = threadIdx.x;
    int m0 = blockIdx.x * 128;
    int b  = m0 / NPIX;
    int p0 = m0 % NPIX;

    int lane = t & 63;
    int wid  = t >> 6;
    int wm = wid & 1;
    int wn = wid >> 1;
    int lr = lane & 15;
    int lk = lane >> 4;

    f4 acc[4][3] = {};

    #pragma unroll
    for (int ks = 0; ks < 6; ks++) {
        const _Float16* abase = ah + (size_t)(b * NHEADS + ks) * NPIX * HD;
        f16x8 af[4], bf[3];
        #pragma unroll
        for (int mi = 0; mi < 4; mi++)
            af[mi] = *(const f16x8*)&abase[(size_t)(p0 + wm * 64 + mi * 16 + lr) * HD + lk * 8];
        #pragma unroll
        for (int ni = 0; ni < 3; ni++)
            bf[ni] = *(const f16x8*)&woT[(size_t)(wn * 48 + ni * 16 + lr) * 192 + ks * 32 + lk * 8];
        #pragma unroll
        for (int mi = 0; mi < 4; mi++)
            #pragma unroll
            for (int ni = 0; ni < 3; ni++)
                acc[mi][ni] = __builtin_amdgcn_mfma_f32_16x16x32_f16(af[mi], bf[ni], acc[mi][ni], 0, 0, 0);
    }

    #pragma unroll
    for (int ni = 0; ni < 3; ni++) {
        int n = wn * 48 + ni * 16 + lr;
        float bb = bo[n];
        float* obase = outp + ((size_t)b * 192 + n) * NPIX + p0 + wm * 64;
        #pragma unroll
        for (int mi = 0; mi < 4; mi++) {
            f4 v = acc[mi][ni];
            v[0] += bb; v[1] += bb; v[2] += bb; v[3] += bb;
            *(f4*)&obase[mi * 16 + lk * 4] = v;
        }
    }
}

extern "C" void kernel_launch(void* const* d_in, const int* in_sizes, int n_in,
                              void* d_out, int out_size, void* d_ws, size_t ws_size,
                              hipStream_t stream) {
    const float* x    = (const float*)d_in[0];
    const float* ctx  = (const float*)d_in[1];
    const float* Wq   = (const float*)d_in[2];
    const float* bq   = (const float*)d_in[3];
    const float* Wk   = (const float*)d_in[4];
    const float* bk   = (const float*)d_in[5];
    const float* Wv   = (const float*)d_in[6];
    const float* bv   = (const float*)d_in[7];
    const float* Wo   = (const float*)d_in[8];
    const float* bo   = (const float*)d_in[9];
    const float* rpb0 = (const float*)d_in[10];
    const float* rpb1 = (const float*)d_in[11];
    const float* rpb2 = (const float*)d_in[12];

    size_t N = (size_t)NB * NHEADS * NPIX * HD;   // 25,165,824 fp16 elements = 50.33MB
    _Float16* qh = (_Float16*)d_ws;
    _Float16* kh = qh + N;
    _Float16* vh = kh + N;
    _Float16* ah = vh + N;
    float* outp = (float*)d_out;

    // parking: WT fp16 in second half of d_out (dead until oproj); woT in qh (dead after na2d)
    _Float16* wt  = (_Float16*)d_out + N;
    _Float16* woT = qh;

    (void)hipFuncSetAttribute((const void*)na2d_mfma,
                              hipFuncAttributeMaxDynamicSharedMemorySize, NA2D_SMEM);

    prep_wt<<<216, 512, 0, stream>>>(Wq, Wk, Wv, wt);
    proj_mfma<<<2048, 512, 0, stream>>>(x, ctx, wt, bq, bk, bv, qh, kh, vh);
    na2d_mfma<<<3072, 512, NA2D_SMEM, stream>>>(qh, kh, vh, rpb0, rpb1, rpb2, ah);
    prep_wo<<<72, 512, 0, stream>>>(Wo, woT);
    oproj_mfma<<<1024, 512, 0, stream>>>(ah, woT, bo, outp);
}